// Round 1
// baseline (2181.522 us; speedup 1.0000x reference)
//
#include <hip/hip_runtime.h>
#include <hip/hip_bf16.h>

#define NIN    512
#define NEVAL  1536
#define NCOLS  2048
#define NOUT   256
#define OUT_BASE (NEVAL - NOUT)   // eval-node index where outputs begin: 1280

// ---------- helpers ----------

__device__ __forceinline__ unsigned short f2bf(float f) {
    __hip_bfloat16 h = __float2bfloat16(f);
    return __builtin_bit_cast(unsigned short, h);
}

// 2 bf16 MACs from packed pairs (a,b are two bf16 each), fp32 accumulate.
__device__ __forceinline__ float bdot2(unsigned a, unsigned b, float acc) {
    float a0 = __uint_as_float(a << 16);
    float a1 = __uint_as_float(a & 0xffff0000u);
    float b0 = __uint_as_float(b << 16);
    float b1 = __uint_as_float(b & 0xffff0000u);
    acc = fmaf(a0, b0, acc);
    acc = fmaf(a1, b1, acc);
    return acc;
}

__device__ __forceinline__ float sigmoid5(float z) {
    float z5 = fminf(fmaxf(5.0f * z, -60.0f), 60.0f);
    return __builtin_amdgcn_rcpf(1.0f + __expf(-z5));
}

// ---------- W fp32 -> bf16 conversion (runs every launch; d_ws is re-poisoned) ----------

__global__ __launch_bounds__(256) void wconv(const float* __restrict__ W,
                                             ushort* __restrict__ Wb, int n4) {
    int i = blockIdx.x * blockDim.x + threadIdx.x;
    if (i < n4) {
        float4 v = ((const float4*)W)[i];
        ushort4 o;
        o.x = f2bf(v.x); o.y = f2bf(v.y); o.z = f2bf(v.z); o.w = f2bf(v.w);
        ((ushort4*)Wb)[i] = o;
    }
}

// ---------- main kernel ----------
// 256 WGs x 256 threads. Each WG owns 16 batch rows; each wave owns 4 rows.
// LDS holds the bf16 activation vector for the 16 rows (exactly 64 KB),
// swizzled: column c of row r lives at (c + 8*r) & 2047 (conflict-free b128).

__global__ __launch_bounds__(256, 1) void ffnet(const float* __restrict__ x,
                                                const float* __restrict__ W,
                                                const ushort* __restrict__ Wb,
                                                const float* __restrict__ bias,
                                                float* __restrict__ out) {
    __shared__ unsigned short O[16 * 2048];   // 65536 B

    const int t    = threadIdx.x;
    const int wave = t >> 6;
    const int lane = t & 63;
    const int rr   = lane >> 4;      // 0..3  (row within wave)
    const int ii   = lane & 15;      // 0..15 (node within block)
    const int r    = wave * 4 + rr;  // local row 0..15
    const long row = (long)blockIdx.x * 16 + r;  // global batch row
    const int rot  = 8 * r;

    // ---- stage x rows into LDS as bf16 (swizzled) ----
    for (int q = 0; q < 8; ++q) {
        int c = q * 64 + ii * 4;
        float4 v = *(const float4*)&x[row * NIN + c];
        ushort4 o4;
        o4.x = f2bf(v.x); o4.y = f2bf(v.y); o4.z = f2bf(v.z); o4.w = f2bf(v.w);
        int s = (c + rot) & 2047;
        *(ushort4*)&O[r * 2048 + s] = o4;
    }
    __syncthreads();

    for (int i0 = 0; i0 < NEVAL; i0 += 16) {
        const int g  = i0 + ii;        // this thread's eval-node index
        const int L0 = NIN + i0;       // columns finished before this block
        const ushort* __restrict__ wrow = Wb + (size_t)g * NCOLS;
        const unsigned short* __restrict__ orow = O + r * 2048;

        // ---- phase A: dot over all completed columns ----
        float acc = bias[g];
        for (int j = 0; j < L0; j += 16) {
            int s0 = (j + rot) & 2047;
            int s1 = (j + 8 + rot) & 2047;
            uint4 ov0 = *(const uint4*)&orow[s0];
            uint4 ov1 = *(const uint4*)&orow[s1];
            uint4 wv0 = *(const uint4*)&wrow[j];
            uint4 wv1 = *(const uint4*)&wrow[j + 8];
            acc = bdot2(ov0.x, wv0.x, acc);
            acc = bdot2(ov0.y, wv0.y, acc);
            acc = bdot2(ov0.z, wv0.z, acc);
            acc = bdot2(ov0.w, wv0.w, acc);
            acc = bdot2(ov1.x, wv1.x, acc);
            acc = bdot2(ov1.y, wv1.y, acc);
            acc = bdot2(ov1.z, wv1.z, acc);
            acc = bdot2(ov1.w, wv1.w, acc);
        }

        // ---- phase B: sequential 16x16 lower-triangular fixup ----
        const int c0 = NIN + i0;
        const float* __restrict__ wdrow = W + (size_t)g * NCOLS + c0;
        float4 wd0 = *(const float4*)&wdrow[0];
        float4 wd1 = *(const float4*)&wdrow[4];
        float4 wd2 = *(const float4*)&wdrow[8];
        float4 wd3 = *(const float4*)&wdrow[12];
        float wdg[16] = {wd0.x, wd0.y, wd0.z, wd0.w,
                         wd1.x, wd1.y, wd1.z, wd1.w,
                         wd2.x, wd2.y, wd2.z, wd2.w,
                         wd3.x, wd3.y, wd3.z, wd3.w};

        float zacc = acc;
        #pragma unroll
        for (int jj = 0; jj < 16; ++jj) {
            float oc = sigmoid5(zacc);                    // valid only on lane ii==jj
            float ob = __shfl(oc, (lane & 0x30) | jj, 64); // broadcast o_jj within row
            if (ii == jj) {
                int c = c0 + jj;
                O[r * 2048 + ((c + rot) & 2047)] = f2bf(oc);
                if (g >= OUT_BASE)
                    out[row * NOUT + (g - OUT_BASE)] = oc;
            }
            if (ii > jj) zacc = fmaf(wdg[jj], ob, zacc);
        }
        __syncthreads();   // block k+1 phase A reads block k's columns
    }
}

// ---------- launch ----------

extern "C" void kernel_launch(void* const* d_in, const int* in_sizes, int n_in,
                              void* d_out, int out_size, void* d_ws, size_t ws_size,
                              hipStream_t stream) {
    const float* x  = (const float*)d_in[0];   // [4096, 512]
    const float* W  = (const float*)d_in[1];   // [1536, 2048]
    const float* b  = (const float*)d_in[2];   // [1536]
    float* out = (float*)d_out;                // [4096, 256]
    ushort* Wb = (ushort*)d_ws;                // bf16 copy of W (6.3 MB)

    int n4 = NEVAL * NCOLS / 4;                // 786432 float4 groups
    wconv<<<n4 / 256, 256, 0, stream>>>(W, Wb, n4);
    ffnet<<<4096 / 16, 256, 0, stream>>>(x, W, Wb, b, out);
}

// Round 2
// 456.578 us; speedup vs baseline: 4.7780x; 4.7780x over previous
//
#include <hip/hip_runtime.h>
#include <hip/hip_bf16.h>

#define NIN    512
#define NEVAL  1536
#define NCOLS  2048
#define NOUT   256
#define OUT_BASE (NEVAL - NOUT)   // 1280

typedef __attribute__((ext_vector_type(8))) short short8;   // 8 bf16 (4 VGPRs)
typedef __attribute__((ext_vector_type(4))) float floatx4;  // MFMA C/D

// ---------- helpers ----------

__device__ __forceinline__ unsigned short f2bf(float f) {
    __hip_bfloat16 h = __float2bfloat16(f);
    return __builtin_bit_cast(unsigned short, h);
}

__device__ __forceinline__ float sigmoid5(float z) {
    float z5 = fminf(fmaxf(5.0f * z, -60.0f), 60.0f);
    return __builtin_amdgcn_rcpf(1.0f + __expf(-z5));
}

// ---------- W fp32 -> bf16 (d_ws re-poisoned every launch, so rerun) ----------

__global__ __launch_bounds__(256) void wconv(const float* __restrict__ W,
                                             ushort* __restrict__ Wb, int n4) {
    int i = blockIdx.x * blockDim.x + threadIdx.x;
    if (i < n4) {
        float4 v = ((const float4*)W)[i];
        ushort4 o;
        o.x = f2bf(v.x); o.y = f2bf(v.y); o.z = f2bf(v.z); o.w = f2bf(v.w);
        ((ushort4*)Wb)[i] = o;
    }
}

// ---------- main kernel ----------
// 256 WGs x 512 threads (8 waves). WG owns 16 batch rows. O[16][2048] bf16 in
// LDS, swizzled: col c of row r at (c + 8r) & 2047 (16B-aligned chunks stay
// aligned since all accesses are multiples of 8 elements).
// Node loop in blocks of 32:
//   phase A: Z[16 rows][32 nodes] += O[16][K] . W[32][K]^T via
//            mfma_f32_16x16x32_bf16. Waves 0-3: nodes 0-15 (K interleaved
//            4-way, stride 128); waves 4-7: nodes 16-31. Partials -> Zred LDS.
//   phase B: 32-step sequential triangular fixup, wave w owns rows 2w,2w+1
//            (lane = rr*32 + ii), fp32 diagonal weights, shfl broadcast.

__global__ __launch_bounds__(512, 1) void ffnet(const float* __restrict__ x,
                                                const float* __restrict__ W,
                                                const ushort* __restrict__ Wb,
                                                const float* __restrict__ bias,
                                                float* __restrict__ out) {
    __shared__ unsigned short O[16 * 2048];  // 64 KB
    __shared__ float Zred[8 * 256];          // 8 KB: [wave][node n][row m]

    const int t    = threadIdx.x;
    const int w    = t >> 6;       // wave 0..7
    const int lane = t & 63;

    // phase-A indices
    const int m16  = lane & 15;    // A row (batch row) / B row (node n)
    const int quad = lane >> 4;    // 0..3
    const int half = w >> 2;       // node half of the 32-block
    const int ksp  = w & 3;        // K-split slot

    // phase-B indices
    const int rr  = lane >> 5;         // 0..1
    const int ii  = lane & 31;         // node within 32-block
    const int r   = (w << 1) | rr;     // local batch row 0..15
    const long row = (long)blockIdx.x * 16 + r;

    // ---- stage x into LDS as bf16 (swizzled): thread -> row t>>5, 16 cols ----
    {
        const int sr = t >> 5;                 // 0..15
        const int cb = (t & 31) * 16;          // 0..496
        const long srow = (long)blockIdx.x * 16 + sr;
        #pragma unroll
        for (int q = 0; q < 4; ++q) {
            int c = cb + q * 4;
            float4 v = *(const float4*)&x[srow * NIN + c];
            ushort4 o4;
            o4.x = f2bf(v.x); o4.y = f2bf(v.y); o4.z = f2bf(v.z); o4.w = f2bf(v.w);
            *(ushort4*)&O[sr * 2048 + ((c + 8 * sr) & 2047)] = o4;
        }
    }
    __syncthreads();

    for (int i0 = 0; i0 < NEVAL; i0 += 32) {
        const int L0 = NIN + i0;   // completed columns (multiple of 32)

        // ---- phase A: MFMA partial dot over this wave's K slice ----
        floatx4 acc = {0.f, 0.f, 0.f, 0.f};
        const ushort* __restrict__ wb = Wb + (size_t)(i0 + half * 16 + m16) * NCOLS;
        const int arow = m16 << 11;
        const int arot = 8 * m16;
        for (int kk = ksp * 32; kk < L0; kk += 128) {
            short8 a = *(const short8*)&O[arow + ((kk + quad * 8 + arot) & 2047)];
            short8 b = *(const short8*)&wb[kk + quad * 8];
            acc = __builtin_amdgcn_mfma_f32_16x16x32_bf16(a, b, acc, 0, 0, 0);
        }
        // D layout: lane holds Z[m = quad*4+reg][n = m16] -> Zred[w][n][m]
        *(floatx4*)&Zred[(w << 8) + (m16 << 4) + (quad << 2)] = acc;
        __syncthreads();

        // ---- gather z for this thread's (row r, node ii) ----
        const int g  = i0 + ii;
        const int c0 = NIN + i0;
        const int h  = ii >> 4;
        const int n  = ii & 15;

        // fp32 diagonal-block weights (only j < ii used)
        const float* __restrict__ wd = W + (size_t)g * NCOLS + c0;
        float wdg[32];
        #pragma unroll
        for (int q = 0; q < 8; ++q)
            *(float4*)&wdg[4 * q] = *(const float4*)&wd[4 * q];

        float zacc = bias[g];
        #pragma unroll
        for (int p2 = 0; p2 < 4; ++p2)
            zacc += Zred[((h * 4 + p2) << 8) + (n << 4) + r];

        // ---- phase B: 32-step sequential triangular fixup ----
        #pragma unroll
        for (int jj = 0; jj < 32; ++jj) {
            float oc = sigmoid5(zacc);                     // valid on ii==jj
            float ob = __shfl(oc, (lane & 32) | jj, 64);   // broadcast in row-half
            if (ii == jj) {
                O[(r << 11) + ((c0 + jj + 8 * r) & 2047)] = f2bf(oc);
                if (g >= OUT_BASE)
                    out[row * NOUT + (g - OUT_BASE)] = oc;
            }
            if (ii > jj) zacc = fmaf(wdg[jj], ob, zacc);
        }
        __syncthreads();   // next phase A reads this block's O columns / Zred reuse
    }
}

// ---------- launch ----------

extern "C" void kernel_launch(void* const* d_in, const int* in_sizes, int n_in,
                              void* d_out, int out_size, void* d_ws, size_t ws_size,
                              hipStream_t stream) {
    const float* x  = (const float*)d_in[0];   // [4096, 512]
    const float* W  = (const float*)d_in[1];   // [1536, 2048]
    const float* b  = (const float*)d_in[2];   // [1536]
    float* out = (float*)d_out;                // [4096, 256]
    ushort* Wb = (ushort*)d_ws;                // bf16 W copy (6.3 MB)

    int n4 = NEVAL * NCOLS / 4;
    wconv<<<n4 / 256, 256, 0, stream>>>(W, Wb, n4);
    ffnet<<<4096 / 16, 512, 0, stream>>>(x, W, Wb, b, out);
}

// Round 4
// 452.856 us; speedup vs baseline: 4.8172x; 1.0082x over previous
//
#include <hip/hip_runtime.h>
#include <hip/hip_bf16.h>

#define NIN    512
#define NEVAL  1536
#define NCOLS  2048
#define NOUT   256
#define OUT_BASE 1280
#define NBLK   48       // NEVAL / 32

typedef __attribute__((ext_vector_type(8))) short short8;   // 8 bf16 (4 VGPRs)
typedef __attribute__((ext_vector_type(4))) float floatx4;  // MFMA C/D

// ---------- helpers ----------

__device__ __forceinline__ unsigned short f2bf(float f) {
    __hip_bfloat16 h = __float2bfloat16(f);
    return __builtin_bit_cast(unsigned short, h);
}
__device__ __forceinline__ unsigned pack2(float a, float b) {
    return (unsigned)f2bf(a) | ((unsigned)f2bf(b) << 16);
}
// sigmoid(clip(5z,-60,60)): clamp dropped — v_exp overflow gives exact 0/1.
__device__ __forceinline__ float sigmoid5(float z) {
    return __builtin_amdgcn_rcpf(1.0f + __expf(-5.0f * z));
}

// ---------- W fp32 -> bf16 (d_ws re-poisoned every launch, so rerun) ----------

__global__ __launch_bounds__(256) void wconv(const float* __restrict__ W,
                                             ushort* __restrict__ Wb, int n4) {
    int i = blockIdx.x * blockDim.x + threadIdx.x;
    if (i < n4) {
        float4 v = ((const float4*)W)[i];
        ushort4 o;
        o.x = f2bf(v.x); o.y = f2bf(v.y); o.z = f2bf(v.z); o.w = f2bf(v.w);
        ((ushort4*)Wb)[i] = o;
    }
}

// ---------- main kernel ----------
// 256 WGs x 1024 threads (16 waves). WG owns 16 batch rows; wave w owns row w.
// O[16][2048] bf16 in LDS, row r rotated by 8r elements (b128-aligned swizzle).
// Per 32-node block k (columns [L0, L0+32), L0 = 512+32k):
//   tail:  one K=32 MFMA over [L0-32, L0) — GATED to ksp==((k+7)&7) so the
//          chunk is counted exactly once per node-half (round-3 bug: all 8
//          K-split waves executed it -> 8x double-count)
//   Zred:  16 waves' partials (2 node-halves x 8 K-splits) -> LDS -> gather
//   main:  MFMAs for block k+1 over [0, L0) — issued BEFORE the chain so the
//          loads/MFMA retire under the chain's latency (no barrier between)
//   chain: 32 sequential steps, readlane broadcast (SALU — no DS on the
//          serial path); wdg[jj] is naturally 0 for jj>=ii (W strictly lower)

__global__ __launch_bounds__(1024) void ffnet(const float* __restrict__ x,
                                              const float* __restrict__ W,
                                              const ushort* __restrict__ Wb,
                                              const float* __restrict__ bias,
                                              float* __restrict__ out) {
    __shared__ unsigned short O[16 * 2048];   // 64 KB
    __shared__ float Zred[16 * 256];          // 16 KB  [wave][lane][reg]

    const int t    = threadIdx.x;
    const int w    = t >> 6;        // wave 0..15
    const int lane = t & 63;

    // phase-A role: half = node half (16 nodes), ksp = K-split slot (stride 256)
    const int m16  = lane & 15;     // A row (batch row) / D col (node)
    const int quad = lane >> 4;     // 0..3
    const int half = w >> 3;        // 0..1
    const int ksp  = w & 7;         // 0..7
    const int arow = m16 << 11;
    const int arot = m16 << 3;

    // chain role: wave w owns local row w; lanes 32-63 mirror lanes 0-31
    const int ii   = lane & 31;     // node within block
    const long row = (long)blockIdx.x * 16 + w;
    const int rot  = w << 3;

    // ---- stage x row w into LDS as bf16 (swizzled) ----
    {
        const float* xr = x + row * NIN + lane * 8;
        float4 v0 = *(const float4*)xr;
        float4 v1 = *(const float4*)(xr + 4);
        uint4 pk;
        pk.x = pack2(v0.x, v0.y); pk.y = pack2(v0.z, v0.w);
        pk.z = pack2(v1.x, v1.y); pk.w = pack2(v1.z, v1.w);
        *(uint4*)&O[(w << 11) + ((lane * 8 + rot) & 2047)] = pk;
    }
    __syncthreads();

    // ---- prologue: main(0) over columns [0, 480) ----
    floatx4 acc = {0.f, 0.f, 0.f, 0.f};
    {
        const ushort* wb = Wb + (size_t)(half * 16 + m16) * NCOLS;
        for (int kk = ksp * 32; kk < NIN - 32; kk += 256) {
            short8 a = *(const short8*)&O[arow + ((kk + quad * 8 + arot) & 2047)];
            short8 b = *(const short8*)&wb[kk + quad * 8];
            acc = __builtin_amdgcn_mfma_f32_16x16x32_bf16(a, b, acc, 0, 0, 0);
        }
    }

    for (int k = 0; k < NBLK; ++k) {
        const int i0 = k << 5;
        const int L0 = NIN + i0;
        const int g  = i0 + ii;     // this lane's eval-node index (mirrored)

        __syncthreads();            // barrier A: chain(k-1) O-writes visible

        // prefetch fp32 diag weights + bias (L2-hot; latency covered by
        // tail + Zred + barrier B + gather before first use in the chain)
        float wdg[32];
        {
            const float* wd = W + (size_t)g * NCOLS + L0;
            #pragma unroll
            for (int q = 0; q < 8; ++q)
                *(float4*)&wdg[q * 4] = *(const float4*)&wd[q * 4];
        }
        float bi = bias[g];

        // tail: K=32 MFMA over [L0-32, L0) — chunk index 15+k, owned by
        // K-split slot (15+k)&7 == (k+7)&7. Exactly one wave per half.
        if (ksp == ((k + 7) & 7)) {
            const ushort* wb = Wb + (size_t)(i0 + half * 16 + m16) * NCOLS;
            const int ts = L0 - 32;
            short8 a = *(const short8*)&O[arow + ((ts + quad * 8 + arot) & 2047)];
            short8 b = *(const short8*)&wb[ts + quad * 8];
            acc = __builtin_amdgcn_mfma_f32_16x16x32_bf16(a, b, acc, 0, 0, 0);
        }

        // D frag: lane q*16+n holds Z[m=4q+reg][n] — store contiguous per lane
        *(floatx4*)&Zred[(w << 8) + (lane << 2)] = acc;
        __syncthreads();            // barrier B

        // gather z for (row w, node ii): sum 8 K-split partials
        const int h = ii >> 4, n = ii & 15;
        const int ridx = ((w >> 2) << 6) + (n << 2) + (w & 3);
        float zacc = bi;
        #pragma unroll
        for (int p = 0; p < 8; ++p)
            zacc += Zred[(((h << 3) + p) << 8) + ridx];

        // issue main(k+1) over [0, L0): reads columns finalized before chain(k),
        // disjoint from chain(k) writes — overlaps the chain's latency stalls
        floatx4 accN = {0.f, 0.f, 0.f, 0.f};
        if (k + 1 < NBLK) {
            const ushort* wb = Wb + (size_t)(i0 + 32 + half * 16 + m16) * NCOLS;
            #pragma unroll 2
            for (int kk = ksp * 32; kk < L0; kk += 256) {
                short8 a = *(const short8*)&O[arow + ((kk + quad * 8 + arot) & 2047)];
                short8 b = *(const short8*)&wb[kk + quad * 8];
                accN = __builtin_amdgcn_mfma_f32_16x16x32_bf16(a, b, accN, 0, 0, 0);
            }
        }

        // chain: 32 sequential sigmoid steps. readlane = SALU broadcast;
        // wdg[jj] == 0 for jj >= ii (W strictly lower-triangular) -> no branch.
        #pragma unroll
        for (int jj = 0; jj < 32; ++jj) {
            float zj = __builtin_bit_cast(float,
                __builtin_amdgcn_readlane(__builtin_bit_cast(int, zacc), jj));
            float oj = sigmoid5(zj);
            zacc = fmaf(wdg[jj], oj, zacc);
        }
        float o = sigmoid5(zacc);

        if (lane < 32) {
            O[(w << 11) + ((L0 + ii + rot) & 2047)] = f2bf(o);
            if (g >= OUT_BASE)
                out[row * NOUT + (g - OUT_BASE)] = o;
        }
        acc = accN;
    }
}

// ---------- launch ----------

extern "C" void kernel_launch(void* const* d_in, const int* in_sizes, int n_in,
                              void* d_out, int out_size, void* d_ws, size_t ws_size,
                              hipStream_t stream) {
    const float* x  = (const float*)d_in[0];   // [4096, 512]
    const float* W  = (const float*)d_in[1];   // [1536, 2048]
    const float* b  = (const float*)d_in[2];   // [1536]
    float* out = (float*)d_out;                // [4096, 256]
    ushort* Wb = (ushort*)d_ws;                // bf16 W copy (6.3 MB)

    int n4 = NEVAL * NCOLS / 4;
    wconv<<<n4 / 256, 256, 0, stream>>>(W, Wb, n4);
    ffnet<<<4096 / 16, 1024, 0, stream>>>(x, W, Wb, b, out);
}